// Round 1
// baseline (569.226 us; speedup 1.0000x reference)
//
#include <hip/hip_runtime.h>
#include <hip/hip_bf16.h>
#include <math.h>

#define DD 128
#define QKVS_W 896   // 256(Q)+256(K)+256(V)+128(skip)
#define CAP 192      // per-chunk edge capacity for online softmax

// ---------------- CSR build ----------------
__global__ __launch_bounds__(256) void count_kernel(const int* __restrict__ edst,
                                                    int* __restrict__ counts, int E) {
  int e = blockIdx.x * 256 + threadIdx.x;
  if (e < E) atomicAdd(&counts[edst[e]], 1);
}

__global__ __launch_bounds__(256) void scan_kernel(const int* __restrict__ counts,
                                                   int* __restrict__ offs,
                                                   int* __restrict__ cursor, int Nn) {
  __shared__ int part[256];
  int tid = threadIdx.x;
  int chunk = (Nn + 255) >> 8;
  int b = tid * chunk, e = min(b + chunk, Nn);
  int s = 0;
  for (int j = b; j < e; ++j) s += counts[j];
  part[tid] = s;
  __syncthreads();
  for (int d = 1; d < 256; d <<= 1) {
    int v = (tid >= d) ? part[tid - d] : 0;
    __syncthreads();
    part[tid] += v;
    __syncthreads();
  }
  int excl = (tid == 0) ? 0 : part[tid - 1];
  for (int j = b; j < e; ++j) { offs[j] = excl; cursor[j] = excl; excl += counts[j]; }
  if (tid == 255) offs[Nn] = part[255];
}

__global__ __launch_bounds__(256) void scatter_kernel(const int* __restrict__ edst,
                                                      int* __restrict__ cursor,
                                                      int* __restrict__ elist, int E) {
  int e = blockIdx.x * 256 + threadIdx.x;
  if (e < E) {
    int pos = atomicAdd(&cursor[edst[e]], 1);
    elist[pos] = e;
  }
}

// ---------------- small precompute ----------------
// ept[t][h*C+c] = hetro_emb[t] . We[:, h*C+c]
__global__ __launch_bounds__(256) void eproj_kernel(const float* __restrict__ hemb,
                                                    const float* __restrict__ We,
                                                    float* __restrict__ ept) {
  int t = blockIdx.x, col = threadIdx.x;  // col < 256
  float s = 0.f;
  for (int k = 0; k < DD; ++k) s = fmaf(hemb[t * DD + k], We[k * 256 + col], s);
  ept[t * 256 + col] = s;
}

__global__ __launch_bounds__(256) void packW_kernel(const float* __restrict__ Wq,
                                                    const float* __restrict__ Wk,
                                                    const float* __restrict__ Wv,
                                                    const float* __restrict__ Ws,
                                                    float* __restrict__ Wcat) {
  int t = blockIdx.x * 256 + threadIdx.x;
  if (t >= DD * QKVS_W) return;
  int k = t / QKVS_W, j = t % QKVS_W;
  float v;
  if (j < 256) v = Wq[k * 256 + j];
  else if (j < 512) v = Wk[k * 256 + (j - 256)];
  else if (j < 768) v = Wv[k * 256 + (j - 512)];
  else v = Ws[k * 128 + (j - 768)];
  Wcat[t] = v;
}

__global__ __launch_bounds__(256) void packB_kernel(const float* __restrict__ bq,
                                                    const float* __restrict__ bk,
                                                    const float* __restrict__ bv,
                                                    const float* __restrict__ bs,
                                                    float* __restrict__ bcat) {
  int j = blockIdx.x * 256 + threadIdx.x;
  if (j >= QKVS_W) return;
  float v;
  if (j < 256) v = bq[j];
  else if (j < 512) v = bk[j - 256];
  else if (j < 768) v = bv[j - 512];
  else v = bs[j - 768];
  bcat[j] = v;
}

// ---------------- tiled f32 GEMM: C = A[M,K]@B[K,N] + bias ----------------
// 64x64 tile, 256 threads, 4x4 micro-tile, BK=16. Assumes M%64==0, N%64==0, K%16==0.
__global__ __launch_bounds__(256) void gemm_bias_kernel(const float* __restrict__ A,
                                                        const float* __restrict__ B,
                                                        const float* __restrict__ bias,
                                                        float* __restrict__ C,
                                                        int M, int N, int K) {
  __shared__ float As[16][64];  // As[k][m] (transposed for b128 reads)
  __shared__ float Bs[16][64];
  const int tid = threadIdx.x;
  const int tx = tid & 15, ty = tid >> 4;
  const int row0 = blockIdx.x * 64, col0 = blockIdx.y * 64;
  const int am = tid >> 2, akq = (tid & 3) << 2;
  const int bk = tid >> 4, bnq = (tid & 15) << 2;
  float acc[4][4] = {{0.f}};
  for (int k0 = 0; k0 < K; k0 += 16) {
    float4 av = *reinterpret_cast<const float4*>(&A[(size_t)(row0 + am) * K + k0 + akq]);
    float4 bv = *reinterpret_cast<const float4*>(&B[(size_t)(k0 + bk) * N + col0 + bnq]);
    __syncthreads();
    As[akq + 0][am] = av.x; As[akq + 1][am] = av.y;
    As[akq + 2][am] = av.z; As[akq + 3][am] = av.w;
    *reinterpret_cast<float4*>(&Bs[bk][bnq]) = bv;
    __syncthreads();
#pragma unroll
    for (int kk = 0; kk < 16; ++kk) {
      float a[4], b[4];
      *reinterpret_cast<float4*>(a) = *reinterpret_cast<const float4*>(&As[kk][ty << 2]);
      *reinterpret_cast<float4*>(b) = *reinterpret_cast<const float4*>(&Bs[kk][tx << 2]);
#pragma unroll
      for (int i = 0; i < 4; ++i)
#pragma unroll
        for (int j = 0; j < 4; ++j)
          acc[i][j] = fmaf(a[i], b[j], acc[i][j]);
    }
  }
  const float* bp = bias + col0 + (tx << 2);
  const float b0 = bp[0], b1 = bp[1], b2 = bp[2], b3 = bp[3];
#pragma unroll
  for (int i = 0; i < 4; ++i) {
    size_t r = (size_t)(row0 + (ty << 2) + i);
    float4 v = make_float4(acc[i][0] + b0, acc[i][1] + b1, acc[i][2] + b2, acc[i][3] + b3);
    *reinterpret_cast<float4*>(&C[r * N + col0 + (tx << 2)]) = v;
  }
}

// ---------------- fused per-node attention + head-mean + skip + residual + LN ----------------
// One wave (64 lanes) per destination node; lane owns channels c=lane and c=lane+64 per head.
__global__ __launch_bounds__(256) void node_attn_ln_kernel(
    const float* __restrict__ QKVS, const float* __restrict__ ept,
    const float* __restrict__ hpre,
    const int* __restrict__ offs, const int* __restrict__ elist,
    const int* __restrict__ esrc, const int* __restrict__ etyp,
    const float* __restrict__ gamma, const float* __restrict__ beta,
    float* __restrict__ hln, int Nn) {
  __shared__ float sl0[4][CAP];
  __shared__ float sl1[4][CAP];
  __shared__ int ssrc[4][CAP];
  __shared__ int styp[4][CAP];
  const int w = threadIdx.x >> 6, lane = threadIdx.x & 63;
  const int i = (blockIdx.x << 2) + w;
  if (i >= Nn) return;
  const float scale = 0.08838834764831845f;  // 1/sqrt(128)
  const float* qrow = QKVS + (size_t)i * QKVS_W;
  const float q0a = qrow[lane], q0b = qrow[lane + 64];
  const float q1a = qrow[lane + 128], q1b = qrow[lane + 192];
  float m0 = -1e30f, m1 = -1e30f, s0 = 0.f, s1 = 0.f;
  float acc0a = 0.f, acc0b = 0.f, acc1a = 0.f, acc1b = 0.f;
  const int ebeg = offs[i], eend = offs[i + 1];
  for (int cs = ebeg; cs < eend; cs += CAP) {
    const int cnt = min(CAP, eend - cs);
    float cm0 = -1e30f, cm1 = -1e30f;
    for (int j = 0; j < cnt; ++j) {
      const int eid = elist[cs + j];
      const int src = esrc[eid], typ = etyp[eid];
      const float* krow = QKVS + (size_t)src * QKVS_W + 256;
      const float* erow = ept + (typ << 8);
      float d0 = q0a * (krow[lane] + erow[lane]) + q0b * (krow[lane + 64] + erow[lane + 64]);
      float d1 = q1a * (krow[lane + 128] + erow[lane + 128]) +
                 q1b * (krow[lane + 192] + erow[lane + 192]);
#pragma unroll
      for (int o = 32; o; o >>= 1) { d0 += __shfl_xor(d0, o); d1 += __shfl_xor(d1, o); }
      d0 *= scale; d1 *= scale;
      if (lane == 0) { sl0[w][j] = d0; sl1[w][j] = d1; ssrc[w][j] = src; styp[w][j] = typ; }
      cm0 = fmaxf(cm0, d0); cm1 = fmaxf(cm1, d1);
    }
    const float nm0 = fmaxf(m0, cm0), nm1 = fmaxf(m1, cm1);
    const float r0 = __expf(m0 - nm0), r1 = __expf(m1 - nm1);
    s0 *= r0; acc0a *= r0; acc0b *= r0;
    s1 *= r1; acc1a *= r1; acc1b *= r1;
    m0 = nm0; m1 = nm1;
    __threadfence_block();
    float ls0 = 0.f, ls1 = 0.f;
#pragma unroll
    for (int u = 0; u < CAP / 64; ++u) {
      int j = lane + (u << 6);
      if (j < cnt) {
        float e0 = __expf(sl0[w][j] - m0);
        float e1 = __expf(sl1[w][j] - m1);
        sl0[w][j] = e0; sl1[w][j] = e1;
        ls0 += e0; ls1 += e1;
      }
    }
#pragma unroll
    for (int o = 32; o; o >>= 1) { ls0 += __shfl_xor(ls0, o); ls1 += __shfl_xor(ls1, o); }
    s0 += ls0; s1 += ls1;
    __threadfence_block();
    for (int j = 0; j < cnt; ++j) {
      const float e0 = sl0[w][j], e1 = sl1[w][j];
      const int src = ssrc[w][j], typ = styp[w][j];
      const float* vrow = QKVS + (size_t)src * QKVS_W + 512;
      const float* erow = ept + (typ << 8);
      acc0a = fmaf(vrow[lane] + erow[lane], e0, acc0a);
      acc0b = fmaf(vrow[lane + 64] + erow[lane + 64], e0, acc0b);
      acc1a = fmaf(vrow[lane + 128] + erow[lane + 128], e1, acc1a);
      acc1b = fmaf(vrow[lane + 192] + erow[lane + 192], e1, acc1b);
    }
  }
  const float inv0 = 1.f / (s0 + 1e-16f), inv1 = 1.f / (s1 + 1e-16f);
  const float ga = 0.5f * (acc0a * inv0 + acc1a * inv1);
  const float gb = 0.5f * (acc0b * inv0 + acc1b * inv1);
  const float* srow = QKVS + (size_t)i * QKVS_W + 768;
  const float* prow = hpre + (size_t)i * DD;
  const float x0 = ga + srow[lane] + prow[lane];
  const float x1 = gb + srow[lane + 64] + prow[lane + 64];
  float sm = x0 + x1;
#pragma unroll
  for (int o = 32; o; o >>= 1) sm += __shfl_xor(sm, o);
  const float mu = sm * (1.f / 128.f);
  const float dx0 = x0 - mu, dx1 = x1 - mu;
  float vv = dx0 * dx0 + dx1 * dx1;
#pragma unroll
  for (int o = 32; o; o >>= 1) vv += __shfl_xor(vv, o);
  const float rstd = rsqrtf(vv * (1.f / 128.f) + 1e-6f);
  hln[(size_t)i * DD + lane] = dx0 * rstd * gamma[lane] + beta[lane];
  hln[(size_t)i * DD + 64 + lane] = dx1 * rstd * gamma[lane + 64] + beta[lane + 64];
}

__global__ __launch_bounds__(256) void gather_kernel(const float* __restrict__ h,
                                                     const int* __restrict__ idx,
                                                     float* __restrict__ out, int Bm) {
  int t = blockIdx.x * 256 + threadIdx.x;
  if (t < Bm * DD) {
    int b = t >> 7, c = t & 127;
    out[t] = h[(size_t)idx[b] * DD + c];
  }
}

extern "C" void kernel_launch(void* const* d_in, const int* in_sizes, int n_in,
                              void* d_out, int out_size, void* d_ws, size_t ws_size,
                              hipStream_t stream) {
  const float* x    = (const float*)d_in[0];
  const float* hemb = (const float*)d_in[1];
  const float* Wq   = (const float*)d_in[2];
  const float* bq   = (const float*)d_in[3];
  const float* Wk   = (const float*)d_in[4];
  const float* bk   = (const float*)d_in[5];
  const float* Wv   = (const float*)d_in[6];
  const float* bv   = (const float*)d_in[7];
  const float* We   = (const float*)d_in[8];
  const float* Wsk  = (const float*)d_in[9];
  const float* bsk  = (const float*)d_in[10];
  const float* lng  = (const float*)d_in[11];
  const float* lnb  = (const float*)d_in[12];
  const float* fw1  = (const float*)d_in[13];
  const float* fb1  = (const float*)d_in[14];
  const float* fw2  = (const float*)d_in[15];
  const float* fb2  = (const float*)d_in[16];
  const int* eidx   = (const int*)d_in[17];
  const int* etyp   = (const int*)d_in[18];
  const int* midx   = (const int*)d_in[19];

  const int Nn = in_sizes[0] / DD;     // 16000
  const int E = in_sizes[18];          // 256000
  const int Bm = in_sizes[19];         // 64
  const int ntypes = in_sizes[1] / DD; // 10
  const int Lc = 2;
  const int II = in_sizes[14] / Lc;    // 512

  const int* esrc = eidx;
  const int* edst = eidx + E;

  float* fws = (float*)d_ws;
  size_t off = 0;
  float* QKVS = fws + off; off += (size_t)Nn * QKVS_W;
  float* T1 = QKVS;  // alias: Nn*512 <= Nn*896, QKVS dead when T1 is written
  float* hlnb = fws + off; off += (size_t)Nn * DD;
  float* h1 = fws + off; off += (size_t)Nn * DD;
  float* h2 = fws + off; off += (size_t)Nn * DD;
  float* ept = fws + off; off += (size_t)ntypes * 256;
  float* Wcat = fws + off; off += (size_t)DD * QKVS_W;
  float* bcat = fws + off; off += QKVS_W;
  int* ibase = (int*)(fws + off);
  int* counts = ibase;
  int* offs = ibase + Nn;
  int* cursor = ibase + 2 * Nn + 1;
  int* elist = ibase + 3 * Nn + 1;

  hipMemsetAsync(counts, 0, (size_t)Nn * sizeof(int), stream);
  count_kernel<<<(E + 255) / 256, 256, 0, stream>>>(edst, counts, E);
  scan_kernel<<<1, 256, 0, stream>>>(counts, offs, cursor, Nn);
  scatter_kernel<<<(E + 255) / 256, 256, 0, stream>>>(edst, cursor, elist, E);
  eproj_kernel<<<ntypes, 256, 0, stream>>>(hemb, We, ept);
  packW_kernel<<<(DD * QKVS_W + 255) / 256, 256, 0, stream>>>(Wq, Wk, Wv, Wsk, Wcat);
  packB_kernel<<<(QKVS_W + 255) / 256, 256, 0, stream>>>(bq, bk, bv, bsk, bcat);

  const float* h = x;
  for (int l = 0; l < Lc; ++l) {
    float* hout = (l == 0) ? h1 : h2;
    dim3 g1(Nn / 64, QKVS_W / 64);
    gemm_bias_kernel<<<g1, 256, 0, stream>>>(h, Wcat, bcat, QKVS, Nn, QKVS_W, DD);
    node_attn_ln_kernel<<<(Nn + 3) / 4, 256, 0, stream>>>(
        QKVS, ept, h, offs, elist, esrc, etyp, lng + l * DD, lnb + l * DD, hlnb, Nn);
    dim3 g2(Nn / 64, II / 64);
    gemm_bias_kernel<<<g2, 256, 0, stream>>>(hlnb, fw1 + (size_t)l * DD * II, fb1 + l * II,
                                             T1, Nn, II, DD);
    dim3 g3(Nn / 64, DD / 64);
    gemm_bias_kernel<<<g3, 256, 0, stream>>>(T1, fw2 + (size_t)l * II * DD, fb2 + l * DD,
                                             hout, Nn, DD, II);
    h = hout;
  }
  gather_kernel<<<(Bm * DD + 255) / 256, 256, 0, stream>>>(h2, midx, (float*)d_out, Bm);
}

// Round 2
// 333.815 us; speedup vs baseline: 1.7052x; 1.7052x over previous
//
#include <hip/hip_runtime.h>
#include <hip/hip_bf16.h>
#include <math.h>

#define DD 128
#define QW 896       // 256(Q)+256(K)+256(V)+128(skip), f16 row width
#define CAP 96       // per-chunk edge capacity for online softmax

typedef _Float16 f16x8 __attribute__((ext_vector_type(8)));
typedef _Float16 f16x4 __attribute__((ext_vector_type(4)));
typedef float f32x4 __attribute__((ext_vector_type(4)));

// ---------------- CSR build ----------------
__global__ __launch_bounds__(256) void count_kernel(const int* __restrict__ edst,
                                                    int* __restrict__ counts, int E) {
  int e = blockIdx.x * 256 + threadIdx.x;
  if (e < E) atomicAdd(&counts[edst[e]], 1);
}

__global__ __launch_bounds__(256) void scan_kernel(const int* __restrict__ counts,
                                                   int* __restrict__ offs,
                                                   int* __restrict__ cursor, int Nn) {
  __shared__ int part[256];
  int tid = threadIdx.x;
  int chunk = (Nn + 255) >> 8;
  int b = tid * chunk, e = min(b + chunk, Nn);
  int s = 0;
  for (int j = b; j < e; ++j) s += counts[j];
  part[tid] = s;
  __syncthreads();
  for (int d = 1; d < 256; d <<= 1) {
    int v = (tid >= d) ? part[tid - d] : 0;
    __syncthreads();
    part[tid] += v;
    __syncthreads();
  }
  int excl = (tid == 0) ? 0 : part[tid - 1];
  for (int j = b; j < e; ++j) { offs[j] = excl; cursor[j] = excl; excl += counts[j]; }
  if (tid == 255) offs[Nn] = part[255];
}

__global__ __launch_bounds__(256) void scatter_kernel(const int* __restrict__ edst,
                                                      int* __restrict__ cursor,
                                                      int* __restrict__ elist, int E) {
  int e = blockIdx.x * 256 + threadIdx.x;
  if (e < E) {
    int pos = atomicAdd(&cursor[edst[e]], 1);
    elist[pos] = e;
  }
}

// ---------------- small precompute (f16 packs / transposes) ----------------
__global__ __launch_bounds__(256) void eproj_kernel(const float* __restrict__ hemb,
                                                    const float* __restrict__ We,
                                                    _Float16* __restrict__ epth) {
  int t = blockIdx.x, col = threadIdx.x;  // col < 256
  float s = 0.f;
  for (int k = 0; k < DD; ++k) s = fmaf(hemb[t * DD + k], We[k * 256 + col], s);
  epth[t * 256 + col] = (_Float16)s;
}

// WcatT[n][k] (f16), n<896, k<128
__global__ __launch_bounds__(256) void packWT_kernel(const float* __restrict__ Wq,
                                                     const float* __restrict__ Wk,
                                                     const float* __restrict__ Wv,
                                                     const float* __restrict__ Ws,
                                                     _Float16* __restrict__ WcatT) {
  int t = blockIdx.x * 256 + threadIdx.x;
  if (t >= QW * DD) return;
  int n = t >> 7, k = t & 127;
  float v;
  if (n < 256) v = Wq[k * 256 + n];
  else if (n < 512) v = Wk[k * 256 + (n - 256)];
  else if (n < 768) v = Wv[k * 256 + (n - 512)];
  else v = Ws[k * 128 + (n - 768)];
  WcatT[t] = (_Float16)v;
}

__global__ __launch_bounds__(256) void packB_kernel(const float* __restrict__ bq,
                                                    const float* __restrict__ bk,
                                                    const float* __restrict__ bv,
                                                    const float* __restrict__ bs,
                                                    float* __restrict__ bcat) {
  int j = blockIdx.x * 256 + threadIdx.x;
  if (j >= QW) return;
  float v;
  if (j < 256) v = bq[j];
  else if (j < 512) v = bk[j - 256];
  else if (j < 768) v = bv[j - 512];
  else v = bs[j - 768];
  bcat[j] = v;
}

// fw1:[2][128][512] -> fw1T:[2][512][128] ; fw2:[2][512][128] -> fw2T:[2][128][512]
__global__ __launch_bounds__(256) void packFFNT_kernel(const float* __restrict__ fw1,
                                                       const float* __restrict__ fw2,
                                                       _Float16* __restrict__ fw1T,
                                                       _Float16* __restrict__ fw2T) {
  const int PER = 2 * 128 * 512;
  int t = blockIdx.x * 256 + threadIdx.x;
  if (t < PER) {
    int l = t >> 16, r = t & 65535;
    int n = r >> 7, k = r & 127;                  // n<512, k<128
    fw1T[t] = (_Float16)fw1[(l << 16) + k * 512 + n];
  } else if (t < 2 * PER) {
    int u = t - PER;
    int l = u >> 16, r = u & 65535;
    int n = r >> 9, k = r & 511;                  // n<128, k<512
    fw2T[u] = (_Float16)fw2[(l << 16) + k * 128 + n];
  }
}

__global__ __launch_bounds__(256) void castx_kernel(const float* __restrict__ x,
                                                    _Float16* __restrict__ xh, int n4) {
  int t = blockIdx.x * 256 + threadIdx.x;
  if (t < n4) {
    float4 v = *reinterpret_cast<const float4*>(&x[t * 4]);
    f16x4 o; o[0] = (_Float16)v.x; o[1] = (_Float16)v.y; o[2] = (_Float16)v.z; o[3] = (_Float16)v.w;
    *reinterpret_cast<f16x4*>(&xh[t * 4]) = o;
  }
}

// ---------------- MFMA f16 GEMM: C = A[M,K] @ Bt[N,K]^T + bias ----------------
// 128x128 block, 4 waves (2x2), each wave 64x64 = 4x4 fragments of 16x16x32.
// No LDS: fragments loaded straight from global (L1/L2-resident tiles).
__global__ __launch_bounds__(256) void gemm_tn_f16(const _Float16* __restrict__ A,
                                                   const _Float16* __restrict__ Bt,
                                                   const float* __restrict__ bias,
                                                   float* __restrict__ Cf,
                                                   _Float16* __restrict__ Ch,
                                                   int M, int N, int K) {
  const int tid = threadIdx.x;
  const int wid = tid >> 6, lane = tid & 63;
  const int wr = wid >> 1, wc = wid & 1;
  const int il = lane & 15, g = lane >> 4;
  const int row0 = blockIdx.x * 128 + wr * 64;
  const int col0 = blockIdx.y * 128 + wc * 64;
  const _Float16* Ap = A + (size_t)(row0 + il) * K + 8 * g;
  const _Float16* Bp = Bt + (size_t)(col0 + il) * K + 8 * g;
  f32x4 acc[4][4];
#pragma unroll
  for (int a = 0; a < 4; ++a)
#pragma unroll
    for (int b = 0; b < 4; ++b) acc[a][b] = (f32x4){0.f, 0.f, 0.f, 0.f};
  for (int k0 = 0; k0 < K; k0 += 32) {
    f16x8 af[4], bf[4];
#pragma unroll
    for (int f = 0; f < 4; ++f) {
      af[f] = *reinterpret_cast<const f16x8*>(Ap + (size_t)(f * 16) * K + k0);
      bf[f] = *reinterpret_cast<const f16x8*>(Bp + (size_t)(f * 16) * K + k0);
    }
#pragma unroll
    for (int fi = 0; fi < 4; ++fi)
#pragma unroll
      for (int fj = 0; fj < 4; ++fj)
        acc[fi][fj] = __builtin_amdgcn_mfma_f32_16x16x32_f16(af[fi], bf[fj], acc[fi][fj], 0, 0, 0);
  }
#pragma unroll
  for (int fj = 0; fj < 4; ++fj) {
    const int col = col0 + fj * 16 + il;
    const float b = bias[col];
#pragma unroll
    for (int fi = 0; fi < 4; ++fi) {
#pragma unroll
      for (int i = 0; i < 4; ++i) {
        const int row = row0 + fi * 16 + g * 4 + i;
        const float v = acc[fi][fj][i] + b;
        if (Cf) Cf[(size_t)row * N + col] = v;
        if (Ch) Ch[(size_t)row * N + col] = (_Float16)v;
      }
    }
  }
}

// ---------------- fused per-node attention + head-mean + skip + residual + LN ----------------
// One wave per destination node; lane owns 4 contiguous channels (lane*4..+3).
// Lanes 0-31 = head 0 (c 0..127), lanes 32-63 = head 1 (c 128..255).
__global__ __launch_bounds__(256) void node_attn_ln_kernel(
    const _Float16* __restrict__ QKVSh, const _Float16* __restrict__ epth,
    const float* __restrict__ hpre,
    const int* __restrict__ offs, const int* __restrict__ elist,
    const int* __restrict__ esrc, const int* __restrict__ etyp,
    const float* __restrict__ gamma, const float* __restrict__ beta,
    _Float16* __restrict__ hlnh, int Nn) {
  __shared__ float sl0[4][CAP], sl1[4][CAP];
  __shared__ int ssrc[4][CAP], styp[4][CAP];
  const int w = threadIdx.x >> 6, lane = threadIdx.x & 63;
  const int i = blockIdx.x * 4 + w;
  if (i >= Nn) return;
  const int c4 = lane * 4;
  const bool hd0 = lane < 32;
  const float scale = 0.08838834764831845f;  // 1/sqrt(128)
  float q[4];
  {
    f16x4 qv = *reinterpret_cast<const f16x4*>(QKVSh + (size_t)i * QW + c4);
#pragma unroll
    for (int t = 0; t < 4; ++t) q[t] = (float)qv[t];
  }
  float m0 = -1e30f, m1 = -1e30f, s0 = 0.f, s1 = 0.f;
  float acc[4] = {0.f, 0.f, 0.f, 0.f};
  const int ebeg = offs[i], eend = offs[i + 1];
  for (int cs = ebeg; cs < eend; cs += CAP) {
    const int cnt = min(CAP, eend - cs);
    for (int j = lane; j < cnt; j += 64) {
      int eid = elist[cs + j];
      ssrc[w][j] = esrc[eid];
      styp[w][j] = etyp[eid];
    }
    __threadfence_block();
    float cm0 = -1e30f, cm1 = -1e30f;
    int srcn = ssrc[w][0], typn = styp[w][0];
    f16x4 kv = *reinterpret_cast<const f16x4*>(QKVSh + (size_t)srcn * QW + 256 + c4);
    f16x4 ev = *reinterpret_cast<const f16x4*>(epth + typn * 256 + c4);
    for (int j = 0; j < cnt; ++j) {
      f16x4 kc = kv, ec = ev;
      if (j + 1 < cnt) {
        srcn = ssrc[w][j + 1]; typn = styp[w][j + 1];
        kv = *reinterpret_cast<const f16x4*>(QKVSh + (size_t)srcn * QW + 256 + c4);
        ev = *reinterpret_cast<const f16x4*>(epth + typn * 256 + c4);
      }
      float d = 0.f;
#pragma unroll
      for (int t = 0; t < 4; ++t) d = fmaf(q[t], (float)kc[t] + (float)ec[t], d);
      d += __shfl_xor(d, 16); d += __shfl_xor(d, 8);
      d += __shfl_xor(d, 4);  d += __shfl_xor(d, 2);  d += __shfl_xor(d, 1);
      d *= scale;
      float dp = __shfl_xor(d, 32);
      float l0 = hd0 ? d : dp, l1 = hd0 ? dp : d;
      if (lane == 0) { sl0[w][j] = l0; sl1[w][j] = l1; }
      cm0 = fmaxf(cm0, l0); cm1 = fmaxf(cm1, l1);
    }
    const float nm0 = fmaxf(m0, cm0), nm1 = fmaxf(m1, cm1);
    const float r0 = __expf(m0 - nm0), r1 = __expf(m1 - nm1);
    const float rme = hd0 ? r0 : r1;
    s0 *= r0; s1 *= r1;
#pragma unroll
    for (int t = 0; t < 4; ++t) acc[t] *= rme;
    m0 = nm0; m1 = nm1;
    __threadfence_block();
    float ls0 = 0.f, ls1 = 0.f;
    for (int j = lane; j < cnt; j += 64) {
      float e0 = __expf(sl0[w][j] - m0);
      float e1 = __expf(sl1[w][j] - m1);
      sl0[w][j] = e0; sl1[w][j] = e1;
      ls0 += e0; ls1 += e1;
    }
#pragma unroll
    for (int o = 32; o; o >>= 1) { ls0 += __shfl_xor(ls0, o); ls1 += __shfl_xor(ls1, o); }
    s0 += ls0; s1 += ls1;
    __threadfence_block();
    srcn = ssrc[w][0]; typn = styp[w][0];
    f16x4 vv = *reinterpret_cast<const f16x4*>(QKVSh + (size_t)srcn * QW + 512 + c4);
    f16x4 ev2 = *reinterpret_cast<const f16x4*>(epth + typn * 256 + c4);
    for (int j = 0; j < cnt; ++j) {
      f16x4 vc = vv, ec = ev2;
      float wj = hd0 ? sl0[w][j] : sl1[w][j];
      if (j + 1 < cnt) {
        srcn = ssrc[w][j + 1]; typn = styp[w][j + 1];
        vv = *reinterpret_cast<const f16x4*>(QKVSh + (size_t)srcn * QW + 512 + c4);
        ev2 = *reinterpret_cast<const f16x4*>(epth + typn * 256 + c4);
      }
#pragma unroll
      for (int t = 0; t < 4; ++t) acc[t] = fmaf((float)vc[t] + (float)ec[t], wj, acc[t]);
    }
  }
  const float inv0 = 1.f / (s0 + 1e-16f), inv1 = 1.f / (s1 + 1e-16f);
  const float invme = hd0 ? inv0 : inv1;
  float g4[4];
#pragma unroll
  for (int t = 0; t < 4; ++t) {
    float a = acc[t] * invme;
    float other = __shfl_xor(a, 32);
    g4[t] = 0.5f * (a + other);
  }
  const int cm = c4 & 127;
  f16x4 sk = *reinterpret_cast<const f16x4*>(QKVSh + (size_t)i * QW + 768 + cm);
  float4 pr = *reinterpret_cast<const float4*>(hpre + (size_t)i * DD + cm);
  float xv[4];
  xv[0] = g4[0] + (float)sk[0] + pr.x;
  xv[1] = g4[1] + (float)sk[1] + pr.y;
  xv[2] = g4[2] + (float)sk[2] + pr.z;
  xv[3] = g4[3] + (float)sk[3] + pr.w;
  float sm = xv[0] + xv[1] + xv[2] + xv[3];
#pragma unroll
  for (int o = 32; o; o >>= 1) sm += __shfl_xor(sm, o);
  const float mu = sm * (1.f / 256.f);
  float dx[4];
  float vvs = 0.f;
#pragma unroll
  for (int t = 0; t < 4; ++t) { dx[t] = xv[t] - mu; vvs += dx[t] * dx[t]; }
#pragma unroll
  for (int o = 32; o; o >>= 1) vvs += __shfl_xor(vvs, o);
  const float rstd = rsqrtf(vvs * (1.f / 256.f) + 1e-6f);
  if (hd0) {
    float4 gm = *reinterpret_cast<const float4*>(gamma + cm);
    float4 bt = *reinterpret_cast<const float4*>(beta + cm);
    f16x4 o;
    o[0] = (_Float16)(dx[0] * rstd * gm.x + bt.x);
    o[1] = (_Float16)(dx[1] * rstd * gm.y + bt.y);
    o[2] = (_Float16)(dx[2] * rstd * gm.z + bt.z);
    o[3] = (_Float16)(dx[3] * rstd * gm.w + bt.w);
    *reinterpret_cast<f16x4*>(hlnh + (size_t)i * DD + c4) = o;
  }
}

__global__ __launch_bounds__(256) void gather_kernel(const float* __restrict__ h,
                                                     const int* __restrict__ idx,
                                                     float* __restrict__ out, int Bm) {
  int t = blockIdx.x * 256 + threadIdx.x;
  if (t < Bm * DD) {
    int b = t >> 7, c = t & 127;
    out[t] = h[(size_t)idx[b] * DD + c];
  }
}

extern "C" void kernel_launch(void* const* d_in, const int* in_sizes, int n_in,
                              void* d_out, int out_size, void* d_ws, size_t ws_size,
                              hipStream_t stream) {
  const float* x    = (const float*)d_in[0];
  const float* hemb = (const float*)d_in[1];
  const float* Wq   = (const float*)d_in[2];
  const float* bq   = (const float*)d_in[3];
  const float* Wk   = (const float*)d_in[4];
  const float* bk   = (const float*)d_in[5];
  const float* Wv   = (const float*)d_in[6];
  const float* bv   = (const float*)d_in[7];
  const float* We   = (const float*)d_in[8];
  const float* Wsk  = (const float*)d_in[9];
  const float* bsk  = (const float*)d_in[10];
  const float* lng  = (const float*)d_in[11];
  const float* lnb  = (const float*)d_in[12];
  const float* fw1  = (const float*)d_in[13];
  const float* fb1  = (const float*)d_in[14];
  const float* fw2  = (const float*)d_in[15];
  const float* fb2  = (const float*)d_in[16];
  const int* eidx   = (const int*)d_in[17];
  const int* etyp   = (const int*)d_in[18];
  const int* midx   = (const int*)d_in[19];

  const int Nn = in_sizes[0] / DD;     // 16000
  const int E = in_sizes[18];          // 256000
  const int Bm = in_sizes[19];         // 64
  const int ntypes = in_sizes[1] / DD; // 10
  const int Lc = 2;
  const int II = in_sizes[14] / Lc;    // 512

  const int* esrc = eidx;
  const int* edst = eidx + E;

  char* p = (char*)d_ws;
  auto alloc = [&](size_t bytes) -> void* {
    void* r = (void*)p;
    p += (bytes + 255) & ~(size_t)255;
    return r;
  };
  float* h1   = (float*)alloc((size_t)Nn * DD * 4);
  float* h2   = (float*)alloc((size_t)Nn * DD * 4);
  float* bcat = (float*)alloc(QW * 4);
  _Float16* QKVSh = (_Float16*)alloc((size_t)Nn * QW * 2);
  _Float16* xh    = (_Float16*)alloc((size_t)Nn * DD * 2);
  _Float16* h1h   = (_Float16*)alloc((size_t)Nn * DD * 2);
  _Float16* hlnh  = (_Float16*)alloc((size_t)Nn * DD * 2);
  _Float16* T1h   = (_Float16*)alloc((size_t)Nn * II * 2);
  _Float16* epth  = (_Float16*)alloc((size_t)ntypes * 256 * 2);
  _Float16* WcatT = (_Float16*)alloc((size_t)QW * DD * 2);
  _Float16* fw1T  = (_Float16*)alloc((size_t)Lc * II * DD * 2);
  _Float16* fw2T  = (_Float16*)alloc((size_t)Lc * DD * II * 2);
  int* counts = (int*)alloc((size_t)Nn * 4);
  int* offs   = (int*)alloc((size_t)(Nn + 1) * 4);
  int* cursor = (int*)alloc((size_t)Nn * 4);
  int* elist  = (int*)alloc((size_t)E * 4);

  hipMemsetAsync(counts, 0, (size_t)Nn * sizeof(int), stream);
  count_kernel<<<(E + 255) / 256, 256, 0, stream>>>(edst, counts, E);
  scan_kernel<<<1, 256, 0, stream>>>(counts, offs, cursor, Nn);
  scatter_kernel<<<(E + 255) / 256, 256, 0, stream>>>(edst, cursor, elist, E);
  eproj_kernel<<<ntypes, 256, 0, stream>>>(hemb, We, epth);
  packWT_kernel<<<(QW * DD + 255) / 256, 256, 0, stream>>>(Wq, Wk, Wv, Wsk, WcatT);
  packB_kernel<<<(QW + 255) / 256, 256, 0, stream>>>(bq, bk, bv, bsk, bcat);
  packFFNT_kernel<<<(2 * 2 * DD * II + 255) / 256, 256, 0, stream>>>(fw1, fw2, fw1T, fw2T);
  castx_kernel<<<(Nn * DD / 4 + 255) / 256, 256, 0, stream>>>(x, xh, Nn * DD / 4);

  for (int l = 0; l < Lc; ++l) {
    const _Float16* Ain = (l == 0) ? xh : h1h;
    const float* hpre = (l == 0) ? x : h1;
    float* hout = (l == 0) ? h1 : h2;
    _Float16* houth = (l == 0) ? h1h : nullptr;
    dim3 g1(Nn / 128, QW / 128);
    gemm_tn_f16<<<g1, 256, 0, stream>>>(Ain, WcatT, bcat, nullptr, QKVSh, Nn, QW, DD);
    node_attn_ln_kernel<<<Nn / 4, 256, 0, stream>>>(
        QKVSh, epth, hpre, offs, elist, esrc, etyp, lng + l * DD, lnb + l * DD, hlnh, Nn);
    dim3 g2(Nn / 128, II / 128);
    gemm_tn_f16<<<g2, 256, 0, stream>>>(hlnh, fw1T + (size_t)l * II * DD, fb1 + l * II,
                                        nullptr, T1h, Nn, II, DD);
    dim3 g3(Nn / 128, DD / 128);
    gemm_tn_f16<<<g3, 256, 0, stream>>>(T1h, fw2T + (size_t)l * DD * II, fb2 + l * DD,
                                        hout, houth, Nn, DD, II);
  }
  gather_kernel<<<(Bm * DD + 255) / 256, 256, 0, stream>>>(h2, midx, (float*)d_out, Bm);
}

// Round 3
// 280.858 us; speedup vs baseline: 2.0267x; 1.1886x over previous
//
#include <hip/hip_runtime.h>
#include <hip/hip_bf16.h>
#include <math.h>

#define DD 128
#define QW 896       // 256(Q)+256(K)+256(V)+128(skip)
#define CAP 96

typedef _Float16 f16x8 __attribute__((ext_vector_type(8)));
typedef _Float16 f16x4 __attribute__((ext_vector_type(4)));
typedef float f32x4 __attribute__((ext_vector_type(4)));

// ---------------- CSR build ----------------
__global__ __launch_bounds__(256) void count_kernel(const int* __restrict__ edst,
                                                    int* __restrict__ counts, int E) {
  int e = blockIdx.x * 256 + threadIdx.x;
  if (e < E) atomicAdd(&counts[edst[e]], 1);
}

__global__ __launch_bounds__(1024) void scan_kernel(const int* __restrict__ counts,
                                                    int* __restrict__ offs,
                                                    int* __restrict__ cursor, int Nn) {
  __shared__ int part[1024];
  int tid = threadIdx.x;
  int chunk = (Nn + 1023) >> 10;
  int b = tid * chunk, e = min(b + chunk, Nn);
  int s = 0;
  for (int j = b; j < e; ++j) s += counts[j];
  part[tid] = s;
  __syncthreads();
  for (int d = 1; d < 1024; d <<= 1) {
    int v = (tid >= d) ? part[tid - d] : 0;
    __syncthreads();
    part[tid] += v;
    __syncthreads();
  }
  int excl = tid ? part[tid - 1] : 0;
  for (int j = b; j < e; ++j) { offs[j] = excl; cursor[j] = excl; excl += counts[j]; }
  if (tid == 1023) offs[Nn] = part[1023];
}

// pack (src | typ<<18) sorted by dst
__global__ __launch_bounds__(256) void scatter_kernel(const int* __restrict__ edst,
                                                      const int* __restrict__ esrc,
                                                      const int* __restrict__ etyp,
                                                      int* __restrict__ cursor,
                                                      unsigned* __restrict__ epk, int E) {
  int e = blockIdx.x * 256 + threadIdx.x;
  if (e < E) {
    int pos = atomicAdd(&cursor[edst[e]], 1);
    epk[pos] = (unsigned)esrc[e] | ((unsigned)etyp[e] << 18);
  }
}

// ---------------- precompute 1: packs, eproj, cast-x, Wf = W1@W2, bf = b1@W2+b2 ----
__global__ __launch_bounds__(256) void precompute1(
    const float* __restrict__ Wq, const float* __restrict__ Wk,
    const float* __restrict__ Wv, const float* __restrict__ Wsk,
    const float* __restrict__ bq, const float* __restrict__ bk,
    const float* __restrict__ bv, const float* __restrict__ bsk,
    const float* __restrict__ hemb, const float* __restrict__ We,
    const float* __restrict__ x,
    const float* __restrict__ fw1, const float* __restrict__ fb1,
    const float* __restrict__ fw2, const float* __restrict__ fb2,
    _Float16* __restrict__ WcatT, float* __restrict__ Wcat, float* __restrict__ bcat,
    _Float16* __restrict__ epth, _Float16* __restrict__ xh,
    float* __restrict__ Wf, float* __restrict__ bfv, int Nn) {
  int t = blockIdx.x * 256 + threadIdx.x;
  if (t < 114688) {  // WcatT f16 [896][128] + Wcat f32 [128][896]
    int n = t >> 7, k = t & 127;
    float v;
    if (n < 256) v = Wq[k * 256 + n];
    else if (n < 512) v = Wk[k * 256 + (n - 256)];
    else if (n < 768) v = Wv[k * 256 + (n - 512)];
    else v = Wsk[k * 128 + (n - 768)];
    WcatT[t] = (_Float16)v;
    Wcat[k * 896 + n] = v;
    return;
  }
  t -= 114688;
  if (t < 896) {
    float v;
    if (t < 256) v = bq[t];
    else if (t < 512) v = bk[t - 256];
    else if (t < 768) v = bv[t - 512];
    else v = bsk[t - 768];
    bcat[t] = v;
    return;
  }
  t -= 896;
  if (t < 2560) {  // eproj f16 [10][256]
    int ty = t >> 8, col = t & 255;
    float s = 0.f;
#pragma unroll 4
    for (int c = 0; c < 128; ++c) s = fmaf(hemb[ty * 128 + c], We[c * 256 + col], s);
    epth[t] = (_Float16)s;
    return;
  }
  t -= 2560;
  if (t < Nn * 16) {  // cast x -> f16, 8 elems/thread
    float4 v0 = *reinterpret_cast<const float4*>(x + (size_t)t * 8);
    float4 v1 = *reinterpret_cast<const float4*>(x + (size_t)t * 8 + 4);
    f16x8 o;
    o[0] = (_Float16)v0.x; o[1] = (_Float16)v0.y; o[2] = (_Float16)v0.z; o[3] = (_Float16)v0.w;
    o[4] = (_Float16)v1.x; o[5] = (_Float16)v1.y; o[6] = (_Float16)v1.z; o[7] = (_Float16)v1.w;
    *reinterpret_cast<f16x8*>(xh + (size_t)t * 8) = o;
    return;
  }
  t -= Nn * 16;
  if (t < 32768) {  // Wf[l][i][j] = fw1[l][i][:] . fw2[l][:][j]
    int l = t >> 14, rem = t & 16383;
    int i2 = rem >> 7, j = rem & 127;
    const float* a = fw1 + (size_t)l * 65536 + i2 * 512;
    const float* b2 = fw2 + (size_t)l * 65536 + j;
    float s = 0.f;
#pragma unroll 4
    for (int k = 0; k < 512; ++k) s = fmaf(a[k], b2[k * 128], s);
    Wf[t] = s;
    return;
  }
  t -= 32768;
  if (t < 256) {  // bfv[l][j] = fb1[l].fw2[l][:,j] + fb2[l][j]
    int l = t >> 7, j = t & 127;
    const float* b1 = fb1 + l * 512;
    const float* w2 = fw2 + (size_t)l * 65536 + j;
    float s = fb2[l * 128 + j];
#pragma unroll 4
    for (int k = 0; k < 512; ++k) s = fmaf(b1[k], w2[k * 128], s);
    bfv[t] = s;
  }
}

// ---------------- precompute 2: BtMid f16 [1024][128] = [Wf0 | Wf0@Wcat]^T, bmid ----
__global__ __launch_bounds__(256) void precompute2(
    const float* __restrict__ Wf, const float* __restrict__ Wcat,
    const float* __restrict__ bfv, const float* __restrict__ bcat,
    _Float16* __restrict__ BtMid, float* __restrict__ bmid) {
  int t = blockIdx.x * 256 + threadIdx.x;
  if (t < 131072) {
    int k = t >> 10, n = t & 1023;
    float v;
    if (n < 128) v = Wf[k * 128 + n];
    else {
      const float* wr = Wf + k * 128;
      const float* wc = Wcat + (n - 128);
      float s = 0.f;
#pragma unroll 4
      for (int c = 0; c < 128; ++c) s = fmaf(wr[c], wc[c * 896], s);
      v = s;
    }
    BtMid[(size_t)n * 128 + k] = (_Float16)v;
    return;
  }
  t -= 131072;
  if (t < 1024) {
    float v;
    if (t < 128) v = bfv[t];
    else {
      const float* wc = Wcat + (t - 128);
      float s = bcat[t - 128];
#pragma unroll 4
      for (int c = 0; c < 128; ++c) s = fmaf(bfv[c], wc[c * 896], s);
      v = s;
    }
    bmid[t] = v;
  }
}

// ---------------- MFMA f16 GEMM: C = A[M,K] @ Bt[N,K]^T + bias, split f32/f16 out ----
__global__ __launch_bounds__(256) void gemm_tn_f16(const _Float16* __restrict__ A,
                                                   const _Float16* __restrict__ Bt,
                                                   const float* __restrict__ bias,
                                                   float* __restrict__ Cf, int NF,
                                                   _Float16* __restrict__ Ch, int choff, int ldh,
                                                   int M, int N, int K) {
  const int tid = threadIdx.x;
  const int wid = tid >> 6, lane = tid & 63;
  const int wr = wid >> 1, wc = wid & 1;
  const int il = lane & 15, g = lane >> 4;
  const int row0 = blockIdx.x * 128 + wr * 64;
  const int col0 = blockIdx.y * 128 + wc * 64;
  const _Float16* Ap = A + (size_t)(row0 + il) * K + 8 * g;
  const _Float16* Bp = Bt + (size_t)(col0 + il) * K + 8 * g;
  f32x4 acc[4][4];
#pragma unroll
  for (int a = 0; a < 4; ++a)
#pragma unroll
    for (int b = 0; b < 4; ++b) acc[a][b] = (f32x4){0.f, 0.f, 0.f, 0.f};
  for (int k0 = 0; k0 < K; k0 += 32) {
    f16x8 af[4], bf[4];
#pragma unroll
    for (int f = 0; f < 4; ++f) {
      af[f] = *reinterpret_cast<const f16x8*>(Ap + (size_t)(f * 16) * K + k0);
      bf[f] = *reinterpret_cast<const f16x8*>(Bp + (size_t)(f * 16) * K + k0);
    }
#pragma unroll
    for (int fi = 0; fi < 4; ++fi)
#pragma unroll
      for (int fj = 0; fj < 4; ++fj)
        acc[fi][fj] = __builtin_amdgcn_mfma_f32_16x16x32_f16(af[fi], bf[fj], acc[fi][fj], 0, 0, 0);
  }
#pragma unroll
  for (int fj = 0; fj < 4; ++fj) {
    const int col = col0 + fj * 16 + il;
    const float b = bias[col];
#pragma unroll
    for (int fi = 0; fi < 4; ++fi) {
#pragma unroll
      for (int i = 0; i < 4; ++i) {
        const int row = row0 + fi * 16 + g * 4 + i;
        const float v = acc[fi][fj][i] + b;
        if (Cf && col < NF) Cf[(size_t)row * NF + col] = v;
        if (Ch && col >= choff) Ch[(size_t)row * ldh + (col - choff)] = (_Float16)v;
      }
    }
  }
}

// ---------------- fused per-node attention + head-mean + skip + residual + LN ----------------
// One wave per node; 32 lanes per edge, 2 edges in flight. Lane owns 8 contiguous
// channels (co = (lane&31)*8); lanes with (lane&31)<16 are head 0, else head 1.
__global__ __launch_bounds__(256) void node_attn_ln_kernel(
    const _Float16* __restrict__ QKVSh, const _Float16* __restrict__ epth,
    const float* __restrict__ hpre,
    const int* __restrict__ offs, const unsigned* __restrict__ epk,
    const float* __restrict__ gamma, const float* __restrict__ beta,
    _Float16* __restrict__ hlnh, int Nn) {
  __shared__ float sl0[4][CAP], sl1[4][CAP];
  __shared__ unsigned spk[4][CAP];
  __shared__ __align__(16) _Float16 elds[2560];
  const int tid = threadIdx.x;
  for (int t = tid; t < 1280; t += 256)
    reinterpret_cast<unsigned*>(elds)[t] = reinterpret_cast<const unsigned*>(epth)[t];
  __syncthreads();
  const int w = tid >> 6, lane = tid & 63;
  const int i = blockIdx.x * 4 + w;
  const int sub = lane >> 5;     // edge slot 0/1
  const int r = lane & 31;
  const int half = r >> 4;       // head of owned channels
  const int co = r << 3;         // channel offset, 8 ch per lane
  const float scale = 0.08838834764831845f;  // 1/sqrt(128)
  float q[8];
  {
    f16x8 qv = *reinterpret_cast<const f16x8*>(QKVSh + (size_t)i * QW + co);
#pragma unroll
    for (int t = 0; t < 8; ++t) q[t] = (float)qv[t];
  }
  float m0 = -1e30f, m1 = -1e30f, s0 = 0.f, s1 = 0.f;
  float acc[8] = {0.f};
  const int ebeg = offs[i], eend = offs[i + 1];
  for (int cs = ebeg; cs < eend; cs += CAP) {
    const int cnt = min(CAP, eend - cs);
    for (int j = lane; j < cnt; j += 64) spk[w][j] = epk[cs + j];
    __threadfence_block();
    // --- QK phase: 2 edges per iteration ---
    {
      int jj = (sub < cnt) ? sub : (cnt - 1);
      unsigned pk = spk[w][jj];
      f16x8 kv = *reinterpret_cast<const f16x8*>(QKVSh + (size_t)(pk & 0x3FFFF) * QW + 256 + co);
      f16x8 ev = *reinterpret_cast<const f16x8*>(elds + ((pk >> 18) << 8) + co);
      for (int j = 0; j < cnt; j += 2) {
        f16x8 kc = kv, ec = ev;
        const bool valid = (j + sub) < cnt;
        int jn = j + 2 + sub; if (jn > cnt - 1) jn = cnt - 1;
        pk = spk[w][jn];
        kv = *reinterpret_cast<const f16x8*>(QKVSh + (size_t)(pk & 0x3FFFF) * QW + 256 + co);
        ev = *reinterpret_cast<const f16x8*>(elds + ((pk >> 18) << 8) + co);
        float d = 0.f;
#pragma unroll
        for (int t = 0; t < 8; ++t) d = fmaf(q[t], (float)kc[t] + (float)ec[t], d);
        d += __shfl_xor(d, 1); d += __shfl_xor(d, 2);
        d += __shfl_xor(d, 4); d += __shfl_xor(d, 8);
        d *= scale;
        if (valid) {
          if (r == 0) sl0[w][j + sub] = d;
          if (r == 16) sl1[w][j + sub] = d;
        }
      }
    }
    __threadfence_block();
    // chunk max
    float lm0 = -1e30f, lm1 = -1e30f;
    for (int j = lane; j < cnt; j += 64) {
      lm0 = fmaxf(lm0, sl0[w][j]); lm1 = fmaxf(lm1, sl1[w][j]);
    }
#pragma unroll
    for (int o = 32; o; o >>= 1) {
      lm0 = fmaxf(lm0, __shfl_xor(lm0, o)); lm1 = fmaxf(lm1, __shfl_xor(lm1, o));
    }
    const float nm0 = fmaxf(m0, lm0), nm1 = fmaxf(m1, lm1);
    const float r0 = __expf(m0 - nm0), r1 = __expf(m1 - nm1);
    const float rme = half ? r1 : r0;
    s0 *= r0; s1 *= r1;
#pragma unroll
    for (int t = 0; t < 8; ++t) acc[t] *= rme;
    m0 = nm0; m1 = nm1;
    // exp pass
    float ls0 = 0.f, ls1 = 0.f;
    for (int j = lane; j < cnt; j += 64) {
      float e0 = __expf(sl0[w][j] - m0);
      float e1 = __expf(sl1[w][j] - m1);
      sl0[w][j] = e0; sl1[w][j] = e1;
      ls0 += e0; ls1 += e1;
    }
#pragma unroll
    for (int o = 32; o; o >>= 1) { ls0 += __shfl_xor(ls0, o); ls1 += __shfl_xor(ls1, o); }
    s0 += ls0; s1 += ls1;
    __threadfence_block();
    // --- V phase: 2 edges per iteration ---
    {
      int jj = (sub < cnt) ? sub : (cnt - 1);
      unsigned pk = spk[w][jj];
      f16x8 vv = *reinterpret_cast<const f16x8*>(QKVSh + (size_t)(pk & 0x3FFFF) * QW + 512 + co);
      f16x8 ev = *reinterpret_cast<const f16x8*>(elds + ((pk >> 18) << 8) + co);
      for (int j = 0; j < cnt; j += 2) {
        f16x8 vc = vv, ec = ev;
        const int jcur = j + sub;
        float wj = 0.f;
        if (jcur < cnt) wj = half ? sl1[w][jcur] : sl0[w][jcur];
        int jn = j + 2 + sub; if (jn > cnt - 1) jn = cnt - 1;
        pk = spk[w][jn];
        vv = *reinterpret_cast<const f16x8*>(QKVSh + (size_t)(pk & 0x3FFFF) * QW + 512 + co);
        ev = *reinterpret_cast<const f16x8*>(elds + ((pk >> 18) << 8) + co);
#pragma unroll
        for (int t = 0; t < 8; ++t) acc[t] = fmaf((float)vc[t] + (float)ec[t], wj, acc[t]);
      }
    }
  }
  // combine edge slots, normalize, head-mean
  const float inv0 = 1.f / (s0 + 1e-16f), inv1 = 1.f / (s1 + 1e-16f);
  const float invme = half ? inv1 : inv0;
  float g[8];
#pragma unroll
  for (int t = 0; t < 8; ++t) {
    float a = acc[t] + __shfl_xor(acc[t], 32);  // sum the two edge slots
    a *= invme;                                 // per-head normalize
    g[t] = 0.5f * (a + __shfl_xor(a, 16));      // mean over heads
  }
  // skip + residual + LN (each 16-lane group holds the full 128 channels)
  const int cm = (r & 15) << 3;
  f16x8 sk = *reinterpret_cast<const f16x8*>(QKVSh + (size_t)i * QW + 768 + cm);
  float4 p0 = *reinterpret_cast<const float4*>(hpre + (size_t)i * DD + cm);
  float4 p1 = *reinterpret_cast<const float4*>(hpre + (size_t)i * DD + cm + 4);
  float xv[8];
  xv[0] = g[0] + (float)sk[0] + p0.x; xv[1] = g[1] + (float)sk[1] + p0.y;
  xv[2] = g[2] + (float)sk[2] + p0.z; xv[3] = g[3] + (float)sk[3] + p0.w;
  xv[4] = g[4] + (float)sk[4] + p1.x; xv[5] = g[5] + (float)sk[5] + p1.y;
  xv[6] = g[6] + (float)sk[6] + p1.z; xv[7] = g[7] + (float)sk[7] + p1.w;
  float sm = 0.f;
#pragma unroll
  for (int t = 0; t < 8; ++t) sm += xv[t];
  sm += __shfl_xor(sm, 1); sm += __shfl_xor(sm, 2);
  sm += __shfl_xor(sm, 4); sm += __shfl_xor(sm, 8);
  const float mu = sm * (1.f / 128.f);
  float vvs = 0.f;
  float dx[8];
#pragma unroll
  for (int t = 0; t < 8; ++t) { dx[t] = xv[t] - mu; vvs += dx[t] * dx[t]; }
  vvs += __shfl_xor(vvs, 1); vvs += __shfl_xor(vvs, 2);
  vvs += __shfl_xor(vvs, 4); vvs += __shfl_xor(vvs, 8);
  const float rstd = rsqrtf(vvs * (1.f / 128.f) + 1e-6f);
  if (lane < 16) {
    float4 gm0 = *reinterpret_cast<const float4*>(gamma + cm);
    float4 gm1 = *reinterpret_cast<const float4*>(gamma + cm + 4);
    float4 bt0 = *reinterpret_cast<const float4*>(beta + cm);
    float4 bt1 = *reinterpret_cast<const float4*>(beta + cm + 4);
    f16x8 o;
    o[0] = (_Float16)(dx[0] * rstd * gm0.x + bt0.x);
    o[1] = (_Float16)(dx[1] * rstd * gm0.y + bt0.y);
    o[2] = (_Float16)(dx[2] * rstd * gm0.z + bt0.z);
    o[3] = (_Float16)(dx[3] * rstd * gm0.w + bt0.w);
    o[4] = (_Float16)(dx[4] * rstd * gm1.x + bt1.x);
    o[5] = (_Float16)(dx[5] * rstd * gm1.y + bt1.y);
    o[6] = (_Float16)(dx[6] * rstd * gm1.z + bt1.z);
    o[7] = (_Float16)(dx[7] * rstd * gm1.w + bt1.w);
    *reinterpret_cast<f16x8*>(hlnh + (size_t)i * DD + cm) = o;
  }
}

// ---------------- final: gather mask rows of hln1, apply layer-1 fused FFN ----------------
__global__ __launch_bounds__(128) void final_kernel(const _Float16* __restrict__ hlnh1,
                                                    const float* __restrict__ Wf,
                                                    const float* __restrict__ bfv,
                                                    const int* __restrict__ midx,
                                                    float* __restrict__ out) {
  __shared__ float rowv[128];
  const int b = blockIdx.x, j = threadIdx.x;
  const int row = midx[b];
  rowv[j] = (float)hlnh1[(size_t)row * DD + j];
  __syncthreads();
  const float* w1 = Wf + 16384 + j;  // Wf1[c][j]
  float s = bfv[128 + j];
#pragma unroll 4
  for (int c = 0; c < 128; ++c) s = fmaf(rowv[c], w1[c * 128], s);
  out[b * DD + j] = s;
}

extern "C" void kernel_launch(void* const* d_in, const int* in_sizes, int n_in,
                              void* d_out, int out_size, void* d_ws, size_t ws_size,
                              hipStream_t stream) {
  const float* x    = (const float*)d_in[0];
  const float* hemb = (const float*)d_in[1];
  const float* Wq   = (const float*)d_in[2];
  const float* bq   = (const float*)d_in[3];
  const float* Wk   = (const float*)d_in[4];
  const float* bk   = (const float*)d_in[5];
  const float* Wv   = (const float*)d_in[6];
  const float* bv   = (const float*)d_in[7];
  const float* We   = (const float*)d_in[8];
  const float* Wsk  = (const float*)d_in[9];
  const float* bsk  = (const float*)d_in[10];
  const float* lng  = (const float*)d_in[11];
  const float* lnb  = (const float*)d_in[12];
  const float* fw1  = (const float*)d_in[13];
  const float* fb1  = (const float*)d_in[14];
  const float* fw2  = (const float*)d_in[15];
  const float* fb2  = (const float*)d_in[16];
  const int* eidx   = (const int*)d_in[17];
  const int* etyp   = (const int*)d_in[18];
  const int* midx   = (const int*)d_in[19];

  const int Nn = in_sizes[0] / DD;     // 16000
  const int E = in_sizes[18];          // 256000

  const int* esrc = eidx;
  const int* edst = eidx + E;

  char* p = (char*)d_ws;
  auto alloc = [&](size_t bytes) -> void* {
    void* r = (void*)p;
    p += (bytes + 255) & ~(size_t)255;
    return r;
  };
  _Float16* QKVSh = (_Float16*)alloc((size_t)Nn * QW * 2);
  _Float16* xh    = (_Float16*)alloc((size_t)Nn * DD * 2);
  _Float16* hln0  = (_Float16*)alloc((size_t)Nn * DD * 2);
  _Float16* hln1  = (_Float16*)alloc((size_t)Nn * DD * 2);
  float*    h1    = (float*)alloc((size_t)Nn * DD * 4);
  _Float16* WcatT = (_Float16*)alloc((size_t)QW * DD * 2);
  float*    Wcat  = (float*)alloc((size_t)DD * QW * 4);
  float*    bcat  = (float*)alloc(QW * 4);
  _Float16* epth  = (_Float16*)alloc(2560 * 2);
  float*    Wf    = (float*)alloc(2 * 128 * 128 * 4);
  float*    bfv   = (float*)alloc(256 * 4);
  _Float16* BtMid = (_Float16*)alloc((size_t)1024 * 128 * 2);
  float*    bmid  = (float*)alloc(1024 * 4);
  int* counts = (int*)alloc((size_t)Nn * 4);
  int* offs   = (int*)alloc((size_t)(Nn + 1) * 4);
  int* cursor = (int*)alloc((size_t)Nn * 4);
  unsigned* epk = (unsigned*)alloc((size_t)E * 4);

  hipMemsetAsync(counts, 0, (size_t)Nn * sizeof(int), stream);
  count_kernel<<<(E + 255) / 256, 256, 0, stream>>>(edst, counts, E);
  scan_kernel<<<1, 1024, 0, stream>>>(counts, offs, cursor, Nn);
  scatter_kernel<<<(E + 255) / 256, 256, 0, stream>>>(edst, esrc, etyp, cursor, epk, E);

  const int p1_threads = 114688 + 896 + 2560 + Nn * 16 + 32768 + 256;
  precompute1<<<(p1_threads + 255) / 256, 256, 0, stream>>>(
      Wq, Wk, Wv, Wsk, bq, bk, bv, bsk, hemb, We, x, fw1, fb1, fw2, fb2,
      WcatT, Wcat, bcat, epth, xh, Wf, bfv, Nn);
  precompute2<<<(131072 + 1024 + 255) / 256, 256, 0, stream>>>(Wf, Wcat, bfv, bcat, BtMid, bmid);

  // Layer 0: QKVS0 = x @ Wcat + bcat
  dim3 g1(Nn / 128, QW / 128);
  gemm_tn_f16<<<g1, 256, 0, stream>>>(xh, WcatT, bcat, nullptr, 0, QKVSh, 0, QW, Nn, QW, DD);
  node_attn_ln_kernel<<<Nn / 4, 256, 0, stream>>>(QKVSh, epth, x, offs, epk,
                                                  lng, lnb, hln0, Nn);
  // Fused: [h1 (f32) | QKVS1 (f16)] = hln0 @ [Wf0 | Wf0@Wcat] + [bf0 | bf0@Wcat+bcat]
  dim3 g2(Nn / 128, 1024 / 128);
  gemm_tn_f16<<<g2, 256, 0, stream>>>(hln0, BtMid, bmid, h1, 128, QKVSh, 128, QW, Nn, 1024, DD);
  node_attn_ln_kernel<<<Nn / 4, 256, 0, stream>>>(QKVSh, epth, h1, offs, epk,
                                                  lng + DD, lnb + DD, hln1, Nn);
  // Final: out = (hln1 @ Wf1 + bf1)[mask]
  final_kernel<<<64, 128, 0, stream>>>(hln1, Wf, bfv, midx, (float*)d_out);
}